// Round 11
// baseline (269.363 us; speedup 1.0000x reference)
//
#include <hip/hip_runtime.h>

#define NBINS 256
#define BATCH 32
#define HW (512 * 512)
#define NSUB 4                 // per-wave sub-histograms (256 threads = 4 waves)
#define BPS 64                 // blocks per sample
#define NBLOCKS (BATCH * BPS)  // 2048

// Packed fixed-point u32 histogram cell (per block):
//   bits [0:18]  : sum of illum * 2^6   (block max 4096*64 = 2^18)
//   bits [19:31] : count                (block max 4096)
#define CNT_SHIFT32 19
#define SUM_MASK32 ((1u << CNT_SHIFT32) - 1)
#define FIX_SCALE32 64.0f  // 2^6

// Tickets live in zero-initialized device globals (NOT d_ws: harness poisons
// d_ws to 0xAA, which breaks the mod-64 winner test — R10's bug).
// Invariant: each call adds exactly BPS per sample / BATCH to g_sticket, so
// at every call entry g_tickets[b] = 0 (mod 64), g_sticket = 0 (mod 32).
__device__ unsigned int g_tickets[BATCH];  // zero-initialized at module load
__device__ unsigned int g_sticket;

__global__ __launch_bounds__(256) void fused_kernel(
    const float* __restrict__ img,          // [B,3,H,W]
    const float* __restrict__ depth,        // [B,1,H,W]
    unsigned int* __restrict__ partials,    // [NBLOCKS, NBINS] plain-stored
    float* __restrict__ sampleLoss,         // [BATCH]
    float* __restrict__ out)
{
    __shared__ unsigned int s_hist[NSUB][NBINS];  // 4 KB
    __shared__ float mean[NBINS];                 // reducer phase
    __shared__ float wsum[4];
    __shared__ unsigned int s_ticket;

    const int tid  = threadIdx.x;
    const int wave = tid >> 6;

    for (int i = tid; i < NSUB * NBINS; i += 256)
        ((unsigned int*)s_hist)[i] = 0u;
    __syncthreads();

    const int b     = blockIdx.x / BPS;
    const int chunk = blockIdx.x % BPS;
    const int pixPerBlock = HW / BPS;  // 4096
    const int base = chunk * pixPerBlock;

    const float4* Rp = (const float4*)(img + (size_t)b * 3 * HW + 0 * HW + base);
    const float4* Gp = (const float4*)(img + (size_t)b * 3 * HW + 1 * HW + base);
    const float4* Bp = (const float4*)(img + (size_t)b * 3 * HW + 2 * HW + base);
    const float4* Dp = (const float4*)(depth + (size_t)b * HW + base);

    const int nvec = pixPerBlock / 4;  // 1024 float4s per block
    for (int i = tid; i < nvec; i += 256) {
        float4 r  = Rp[i];
        float4 g  = Gp[i];
        float4 bl = Bp[i];
        float4 d  = Dp[i];

        float il0 = 0.2f * r.x + 0.7f * g.x + 0.1f * bl.x;
        float il1 = 0.2f * r.y + 0.7f * g.y + 0.1f * bl.y;
        float il2 = 0.2f * r.z + 0.7f * g.z + 0.1f * bl.z;
        float il3 = 0.2f * r.w + 0.7f * g.w + 0.1f * bl.w;

        int k0 = (int)(d.x * 255.0f + 0.5f);
        int k1 = (int)(d.y * 255.0f + 0.5f);
        int k2 = (int)(d.z * 255.0f + 0.5f);
        int k3 = (int)(d.w * 255.0f + 0.5f);
        k0 = min(max(k0, 0), NBINS - 1);
        k1 = min(max(k1, 0), NBINS - 1);
        k2 = min(max(k2, 0), NBINS - 1);
        k3 = min(max(k3, 0), NBINS - 1);

        unsigned int v0 = (1u << CNT_SHIFT32) | (unsigned int)(il0 * FIX_SCALE32 + 0.5f);
        unsigned int v1 = (1u << CNT_SHIFT32) | (unsigned int)(il1 * FIX_SCALE32 + 0.5f);
        unsigned int v2 = (1u << CNT_SHIFT32) | (unsigned int)(il2 * FIX_SCALE32 + 0.5f);
        unsigned int v3 = (1u << CNT_SHIFT32) | (unsigned int)(il3 * FIX_SCALE32 + 0.5f);

        atomicAdd(&s_hist[wave][k0], v0);
        atomicAdd(&s_hist[wave][k1], v1);
        atomicAdd(&s_hist[wave][k2], v2);
        atomicAdd(&s_hist[wave][k3], v3);
    }
    __syncthreads();

    // fold sub-histograms; plain coalesced store of this block's partial
    for (int k = tid; k < NBINS; k += 256) {
        unsigned int v = s_hist[0][k] + s_hist[1][k] + s_hist[2][k] + s_hist[3][k];
        partials[(size_t)blockIdx.x * NBINS + k] = v;
    }

    // ---- ticket: LAST block of this sample reduces it ----
    __threadfence();  // release: partial stores visible device-wide
    if (tid == 0) s_ticket = atomicAdd(&g_tickets[b], 1u);
    __syncthreads();

    if ((s_ticket & (BPS - 1)) == (BPS - 1)) {  // true last arrival (tickets ≡ 0 mod 64 at entry)
        __threadfence();  // acquire

        unsigned int acc_s = 0u, acc_c = 0u;
        const unsigned int* p = partials + (size_t)b * BPS * NBINS;
#pragma unroll 8
        for (int j = 0; j < BPS; ++j) {
            unsigned int v = p[(size_t)j * NBINS + tid];  // coalesced 1KB rows
            acc_s += v & SUM_MASK32;
            acc_c += v >> CNT_SHIFT32;
        }
        mean[tid] = ((float)acc_s * (1.0f / FIX_SCALE32)) / (float)acc_c;
        __syncthreads();

        float v = 0.0f;
        if (tid < NBINS - 1)
            v = fmaxf(mean[tid] - mean[tid + 1], 0.0f);
        for (int off = 32; off > 0; off >>= 1)
            v += __shfl_down(v, off, 64);
        if ((tid & 63) == 0) wsum[tid >> 6] = v;
        __syncthreads();
        if (tid == 0)
            sampleLoss[b] = wsum[0] + wsum[1] + wsum[2] + wsum[3];

        // ---- second-level ticket: last sample's reducer writes the scalar ----
        __threadfence();
        if (tid == 0) s_ticket = atomicAdd(&g_sticket, 1u);
        __syncthreads();

        if ((s_ticket & (BATCH - 1)) == (BATCH - 1)) {
            __threadfence();
            if (tid == 0) {
                float total = 0.0f;
                for (int bb = 0; bb < BATCH; ++bb)  // fixed order -> deterministic
                    total += sampleLoss[bb];
                out[0] = total / (255.0f * (float)BATCH);
            }
        }
    }
}

extern "C" void kernel_launch(void* const* d_in, const int* in_sizes, int n_in,
                              void* d_out, int out_size, void* d_ws, size_t ws_size,
                              hipStream_t stream)
{
    const float* img   = (const float*)d_in[0];
    const float* depth = (const float*)d_in[1];
    float* out = (float*)d_out;

    // workspace: partials (2MB) + sampleLoss[32]; both fully overwritten in
    // dependency order every call -> no zeroing needed.
    char* ws = (char*)d_ws;
    unsigned int* partials   = (unsigned int*)ws;
    float*        sampleLoss = (float*)(ws + (size_t)NBLOCKS * NBINS * sizeof(unsigned int));

    fused_kernel<<<NBLOCKS, 256, 0, stream>>>(img, depth, partials, sampleLoss, out);
}

// Round 12
// 29.246 us; speedup vs baseline: 9.2103x; 9.2103x over previous
//
#include <hip/hip_runtime.h>

#define NBINS 256
#define BATCH 32
#define HW (512 * 512)
#define NSUB 4                 // per-wave sub-histograms (256 threads = 4 waves)
#define BLOCKS_PER_SAMPLE 64   // pinned by u32 packing bounds (cnt<=4096, sum<=2^18)
#define NBLOCKS (BATCH * BLOCKS_PER_SAMPLE)  // 2048

// Packed fixed-point u32 histogram cell (per block):
//   bits [0:18]  : sum of illum * 2^6   (block max 4096*64 = 2^18)
//   bits [19:31] : count                (block max 4096 < 2^13)
#define CNT_SHIFT32 19
#define SUM_MASK32 ((1u << CNT_SHIFT32) - 1)
#define FIX_SCALE32 64.0f  // 2^6

__global__ __launch_bounds__(256) void hist_kernel(
    const float* __restrict__ img,        // [B,3,H,W]
    const float* __restrict__ depth,      // [B,1,H,W]
    unsigned int* __restrict__ partials,  // [NBLOCKS, NBINS] plain-stored
    float* __restrict__ out)              // zeroed here for next kernel's atomics
{
    __shared__ unsigned int s_hist[NSUB][NBINS];  // 4 KB

    const int tid  = threadIdx.x;
    const int wave = tid >> 6;

    // zero the scalar output once per call; kernel boundary makes this
    // visible to reduce_kernel's atomicAdds (no fence needed)
    if (blockIdx.x == 0 && tid == 0) out[0] = 0.0f;

    for (int i = tid; i < NSUB * NBINS; i += 256)
        ((unsigned int*)s_hist)[i] = 0u;
    __syncthreads();

    const int b     = blockIdx.x / BLOCKS_PER_SAMPLE;
    const int chunk = blockIdx.x % BLOCKS_PER_SAMPLE;
    const int pixPerBlock = HW / BLOCKS_PER_SAMPLE;  // 4096
    const int base = chunk * pixPerBlock;

    const float4* Rp = (const float4*)(img + (size_t)b * 3 * HW + 0 * HW + base);
    const float4* Gp = (const float4*)(img + (size_t)b * 3 * HW + 1 * HW + base);
    const float4* Bp = (const float4*)(img + (size_t)b * 3 * HW + 2 * HW + base);
    const float4* Dp = (const float4*)(depth + (size_t)b * HW + base);

    const int nvec = pixPerBlock / 4;  // 1024 float4s per block
    for (int i = tid; i < nvec; i += 256) {
        float4 r  = Rp[i];
        float4 g  = Gp[i];
        float4 bl = Bp[i];
        float4 d  = Dp[i];

        float il0 = 0.2f * r.x + 0.7f * g.x + 0.1f * bl.x;
        float il1 = 0.2f * r.y + 0.7f * g.y + 0.1f * bl.y;
        float il2 = 0.2f * r.z + 0.7f * g.z + 0.1f * bl.z;
        float il3 = 0.2f * r.w + 0.7f * g.w + 0.1f * bl.w;

        int k0 = (int)(d.x * 255.0f + 0.5f);
        int k1 = (int)(d.y * 255.0f + 0.5f);
        int k2 = (int)(d.z * 255.0f + 0.5f);
        int k3 = (int)(d.w * 255.0f + 0.5f);
        k0 = min(max(k0, 0), NBINS - 1);
        k1 = min(max(k1, 0), NBINS - 1);
        k2 = min(max(k2, 0), NBINS - 1);
        k3 = min(max(k3, 0), NBINS - 1);

        unsigned int v0 = (1u << CNT_SHIFT32) | (unsigned int)(il0 * FIX_SCALE32 + 0.5f);
        unsigned int v1 = (1u << CNT_SHIFT32) | (unsigned int)(il1 * FIX_SCALE32 + 0.5f);
        unsigned int v2 = (1u << CNT_SHIFT32) | (unsigned int)(il2 * FIX_SCALE32 + 0.5f);
        unsigned int v3 = (1u << CNT_SHIFT32) | (unsigned int)(il3 * FIX_SCALE32 + 0.5f);

        atomicAdd(&s_hist[wave][k0], v0);
        atomicAdd(&s_hist[wave][k1], v1);
        atomicAdd(&s_hist[wave][k2], v2);
        atomicAdd(&s_hist[wave][k3], v3);
    }
    __syncthreads();

    // fold sub-histograms; plain coalesced store (no global atomics, no memset)
    for (int k = tid; k < NBINS; k += 256) {
        unsigned int v = s_hist[0][k] + s_hist[1][k] + s_hist[2][k] + s_hist[3][k];
        partials[(size_t)blockIdx.x * NBINS + k] = v;
    }
}

// one block per sample: unpack+sum 64 partials, means, relu-diff,
// then atomicAdd the pre-scaled per-sample loss straight into out[0]
__global__ __launch_bounds__(256) void reduce_kernel(
    const unsigned int* __restrict__ partials,  // [NBLOCKS, NBINS]
    float* __restrict__ out)
{
    __shared__ float mean[NBINS];
    __shared__ float wsum[4];

    const int b   = blockIdx.x;
    const int tid = threadIdx.x;  // = bin index

    unsigned int acc_s = 0u, acc_c = 0u;
    const unsigned int* p = partials + (size_t)b * BLOCKS_PER_SAMPLE * NBINS;
#pragma unroll 8
    for (int j = 0; j < BLOCKS_PER_SAMPLE; ++j) {
        unsigned int v = p[(size_t)j * NBINS + tid];  // coalesced rows
        acc_s += v & SUM_MASK32;
        acc_c += v >> CNT_SHIFT32;
    }

    mean[tid] = ((float)acc_s * (1.0f / FIX_SCALE32)) / (float)acc_c;
    __syncthreads();

    float v = 0.0f;
    if (tid < NBINS - 1)
        v = fmaxf(mean[tid] - mean[tid + 1], 0.0f);

    for (int off = 32; off > 0; off >>= 1)
        v += __shfl_down(v, off, 64);
    if ((tid & 63) == 0) wsum[tid >> 6] = v;
    __syncthreads();
    if (tid == 0) {
        float loss_b = wsum[0] + wsum[1] + wsum[2] + wsum[3];
        atomicAdd(out, loss_b * (1.0f / (255.0f * (float)BATCH)));
    }
}

extern "C" void kernel_launch(void* const* d_in, const int* in_sizes, int n_in,
                              void* d_out, int out_size, void* d_ws, size_t ws_size,
                              hipStream_t stream)
{
    const float* img   = (const float*)d_in[0];
    const float* depth = (const float*)d_in[1];
    float* out = (float*)d_out;

    unsigned int* partials = (unsigned int*)d_ws;  // 2 MB, fully overwritten each call

    hist_kernel<<<NBLOCKS, 256, 0, stream>>>(img, depth, partials, out);
    reduce_kernel<<<BATCH, 256, 0, stream>>>(partials, out);
}

// Round 13
// 27.957 us; speedup vs baseline: 9.6348x; 1.0461x over previous
//
#include <hip/hip_runtime.h>

#define NBINS 256
#define BATCH 32
#define HW (512 * 512)
#define NSUB 4                 // per-wave sub-histograms (256 threads = 4 waves)
#define BLOCKS_PER_SAMPLE 32
#define NBLOCKS (BATCH * BLOCKS_PER_SAMPLE)  // 1024

// Packed fixed-point u32 histogram cell (per block, 8192 px):
//   bits [0:17]  : sum of illum * 2^4   (block max 8192*16 = 2^17, illum<1)
//   bits [18:31] : count                (14 bits, max 16383 >= 8192 worst case)
#define CNT_SHIFT32 18
#define SUM_MASK32 ((1u << CNT_SHIFT32) - 1)
#define FIX_SCALE32 16.0f  // 2^4

__global__ __launch_bounds__(256) void hist_kernel(
    const float* __restrict__ img,        // [B,3,H,W]
    const float* __restrict__ depth,      // [B,1,H,W]
    unsigned int* __restrict__ partials,  // [NBLOCKS, NBINS] plain-stored
    float* __restrict__ out)              // zeroed here for reduce's atomics
{
    __shared__ unsigned int s_hist[NSUB][NBINS];  // 4 KB

    const int tid  = threadIdx.x;
    const int wave = tid >> 6;

    // zero the scalar output once per call; kernel boundary orders this
    // before reduce_kernel's atomicAdds
    if (blockIdx.x == 0 && tid == 0) out[0] = 0.0f;

    for (int i = tid; i < NSUB * NBINS; i += 256)
        ((unsigned int*)s_hist)[i] = 0u;
    __syncthreads();

    const int b     = blockIdx.x / BLOCKS_PER_SAMPLE;
    const int chunk = blockIdx.x % BLOCKS_PER_SAMPLE;
    const int pixPerBlock = HW / BLOCKS_PER_SAMPLE;  // 8192
    const int base = chunk * pixPerBlock;

    const float4* Rp = (const float4*)(img + (size_t)b * 3 * HW + 0 * HW + base);
    const float4* Gp = (const float4*)(img + (size_t)b * 3 * HW + 1 * HW + base);
    const float4* Bp = (const float4*)(img + (size_t)b * 3 * HW + 2 * HW + base);
    const float4* Dp = (const float4*)(depth + (size_t)b * HW + base);

    const int nvec = pixPerBlock / 4;  // 2048 float4s per block, 8 iters/thread
    for (int i = tid; i < nvec; i += 256) {
        float4 r  = Rp[i];
        float4 g  = Gp[i];
        float4 bl = Bp[i];
        float4 d  = Dp[i];

        float il0 = 0.2f * r.x + 0.7f * g.x + 0.1f * bl.x;
        float il1 = 0.2f * r.y + 0.7f * g.y + 0.1f * bl.y;
        float il2 = 0.2f * r.z + 0.7f * g.z + 0.1f * bl.z;
        float il3 = 0.2f * r.w + 0.7f * g.w + 0.1f * bl.w;

        int k0 = (int)(d.x * 255.0f + 0.5f);
        int k1 = (int)(d.y * 255.0f + 0.5f);
        int k2 = (int)(d.z * 255.0f + 0.5f);
        int k3 = (int)(d.w * 255.0f + 0.5f);
        k0 = min(max(k0, 0), NBINS - 1);
        k1 = min(max(k1, 0), NBINS - 1);
        k2 = min(max(k2, 0), NBINS - 1);
        k3 = min(max(k3, 0), NBINS - 1);

        unsigned int v0 = (1u << CNT_SHIFT32) | (unsigned int)(il0 * FIX_SCALE32 + 0.5f);
        unsigned int v1 = (1u << CNT_SHIFT32) | (unsigned int)(il1 * FIX_SCALE32 + 0.5f);
        unsigned int v2 = (1u << CNT_SHIFT32) | (unsigned int)(il2 * FIX_SCALE32 + 0.5f);
        unsigned int v3 = (1u << CNT_SHIFT32) | (unsigned int)(il3 * FIX_SCALE32 + 0.5f);

        atomicAdd(&s_hist[wave][k0], v0);
        atomicAdd(&s_hist[wave][k1], v1);
        atomicAdd(&s_hist[wave][k2], v2);
        atomicAdd(&s_hist[wave][k3], v3);
    }
    __syncthreads();

    // fold sub-histograms; plain coalesced store (no global atomics, no memset)
    for (int k = tid; k < NBINS; k += 256) {
        unsigned int v = s_hist[0][k] + s_hist[1][k] + s_hist[2][k] + s_hist[3][k];
        partials[(size_t)blockIdx.x * NBINS + k] = v;
    }
}

// one block per sample: unpack+sum 32 partials, means, relu-diff,
// atomicAdd pre-scaled per-sample loss into out[0]
__global__ __launch_bounds__(256) void reduce_kernel(
    const unsigned int* __restrict__ partials,  // [NBLOCKS, NBINS]
    float* __restrict__ out)
{
    __shared__ float mean[NBINS];
    __shared__ float wsum[4];

    const int b   = blockIdx.x;
    const int tid = threadIdx.x;  // = bin index

    unsigned int acc_s = 0u, acc_c = 0u;  // max 32*2^17=2^22 / 32*8192=2^18: safe
    const unsigned int* p = partials + (size_t)b * BLOCKS_PER_SAMPLE * NBINS;
#pragma unroll 8
    for (int j = 0; j < BLOCKS_PER_SAMPLE; ++j) {
        unsigned int v = p[(size_t)j * NBINS + tid];  // coalesced 1KB rows
        acc_s += v & SUM_MASK32;
        acc_c += v >> CNT_SHIFT32;
    }

    mean[tid] = ((float)acc_s * (1.0f / FIX_SCALE32)) / (float)acc_c;
    __syncthreads();

    float v = 0.0f;
    if (tid < NBINS - 1)
        v = fmaxf(mean[tid] - mean[tid + 1], 0.0f);

    for (int off = 32; off > 0; off >>= 1)
        v += __shfl_down(v, off, 64);
    if ((tid & 63) == 0) wsum[tid >> 6] = v;
    __syncthreads();
    if (tid == 0) {
        float loss_b = wsum[0] + wsum[1] + wsum[2] + wsum[3];
        atomicAdd(out, loss_b * (1.0f / (255.0f * (float)BATCH)));
    }
}

extern "C" void kernel_launch(void* const* d_in, const int* in_sizes, int n_in,
                              void* d_out, int out_size, void* d_ws, size_t ws_size,
                              hipStream_t stream)
{
    const float* img   = (const float*)d_in[0];
    const float* depth = (const float*)d_in[1];
    float* out = (float*)d_out;

    unsigned int* partials = (unsigned int*)d_ws;  // 1 MB, fully overwritten each call

    hist_kernel<<<NBLOCKS, 256, 0, stream>>>(img, depth, partials, out);
    reduce_kernel<<<BATCH, 256, 0, stream>>>(partials, out);
}

// Round 14
// 27.798 us; speedup vs baseline: 9.6900x; 1.0057x over previous
//
#include <hip/hip_runtime.h>

#define NBINS 256
#define BATCH 32
#define HW (512 * 512)
#define NSUB 4                 // per-wave sub-histograms (256 threads = 4 waves)
#define BLOCKS_PER_SAMPLE 32
#define NBLOCKS (BATCH * BLOCKS_PER_SAMPLE)  // 1024
#define NITER 8                // (HW/BLOCKS_PER_SAMPLE)/4/256

// Packed fixed-point u32 histogram cell (per block, 8192 px):
//   bits [0:17]  : sum of illum * 2^4   (block max 8192*16 = 2^17, illum<1)
//   bits [18:31] : count                (14 bits, max 16383 >= 8192 worst case)
#define CNT_SHIFT32 18
#define SUM_MASK32 ((1u << CNT_SHIFT32) - 1)
#define FIX_SCALE32 16.0f  // 2^4

__global__ __launch_bounds__(256) void hist_kernel(
    const float* __restrict__ img,        // [B,3,H,W]
    const float* __restrict__ depth,      // [B,1,H,W]
    unsigned int* __restrict__ partials,  // [NBLOCKS, NBINS] plain-stored
    float* __restrict__ out)              // zeroed here for reduce's atomics
{
    __shared__ unsigned int s_hist[NSUB][NBINS];  // 4 KB

    const int tid  = threadIdx.x;
    const int wave = tid >> 6;

    if (blockIdx.x == 0 && tid == 0) out[0] = 0.0f;

    for (int i = tid; i < NSUB * NBINS; i += 256)
        ((unsigned int*)s_hist)[i] = 0u;
    __syncthreads();

    const int b     = blockIdx.x / BLOCKS_PER_SAMPLE;
    const int chunk = blockIdx.x % BLOCKS_PER_SAMPLE;
    const int pixPerBlock = HW / BLOCKS_PER_SAMPLE;  // 8192
    const int base = chunk * pixPerBlock;

    const float4* Rp = (const float4*)(img + (size_t)b * 3 * HW + 0 * HW + base);
    const float4* Gp = (const float4*)(img + (size_t)b * 3 * HW + 1 * HW + base);
    const float4* Bp = (const float4*)(img + (size_t)b * 3 * HW + 2 * HW + base);
    const float4* Dp = (const float4*)(depth + (size_t)b * HW + base);

    // ---- software-pipelined pixel loop: prefetch it+1 while processing it ----
    float4 r  = Rp[tid];
    float4 g  = Gp[tid];
    float4 bl = Bp[tid];
    float4 d  = Dp[tid];

#pragma unroll
    for (int it = 0; it < NITER; ++it) {
        float4 rn, gn, bln, dn;
        if (it < NITER - 1) {
            const int j = tid + (it + 1) * 256;
            rn  = Rp[j];
            gn  = Gp[j];
            bln = Bp[j];
            dn  = Dp[j];
        }

        float il0 = 0.2f * r.x + 0.7f * g.x + 0.1f * bl.x;
        float il1 = 0.2f * r.y + 0.7f * g.y + 0.1f * bl.y;
        float il2 = 0.2f * r.z + 0.7f * g.z + 0.1f * bl.z;
        float il3 = 0.2f * r.w + 0.7f * g.w + 0.1f * bl.w;

        int k0 = (int)(d.x * 255.0f + 0.5f);
        int k1 = (int)(d.y * 255.0f + 0.5f);
        int k2 = (int)(d.z * 255.0f + 0.5f);
        int k3 = (int)(d.w * 255.0f + 0.5f);
        k0 = min(max(k0, 0), NBINS - 1);
        k1 = min(max(k1, 0), NBINS - 1);
        k2 = min(max(k2, 0), NBINS - 1);
        k3 = min(max(k3, 0), NBINS - 1);

        unsigned int v0 = (1u << CNT_SHIFT32) | (unsigned int)(il0 * FIX_SCALE32 + 0.5f);
        unsigned int v1 = (1u << CNT_SHIFT32) | (unsigned int)(il1 * FIX_SCALE32 + 0.5f);
        unsigned int v2 = (1u << CNT_SHIFT32) | (unsigned int)(il2 * FIX_SCALE32 + 0.5f);
        unsigned int v3 = (1u << CNT_SHIFT32) | (unsigned int)(il3 * FIX_SCALE32 + 0.5f);

        atomicAdd(&s_hist[wave][k0], v0);
        atomicAdd(&s_hist[wave][k1], v1);
        atomicAdd(&s_hist[wave][k2], v2);
        atomicAdd(&s_hist[wave][k3], v3);

        r = rn; g = gn; bl = bln; d = dn;
    }
    __syncthreads();

    // fold sub-histograms; plain coalesced store
    for (int k = tid; k < NBINS; k += 256) {
        unsigned int v = s_hist[0][k] + s_hist[1][k] + s_hist[2][k] + s_hist[3][k];
        partials[(size_t)blockIdx.x * NBINS + k] = v;
    }
}

// one block per sample: unpack+sum 32 partials, means, relu-diff,
// atomicAdd pre-scaled per-sample loss into out[0]
__global__ __launch_bounds__(256) void reduce_kernel(
    const unsigned int* __restrict__ partials,  // [NBLOCKS, NBINS]
    float* __restrict__ out)
{
    __shared__ float mean[NBINS];
    __shared__ float wsum[4];

    const int b   = blockIdx.x;
    const int tid = threadIdx.x;  // = bin index

    unsigned int acc_s = 0u, acc_c = 0u;  // max 32*2^17=2^22 / 32*8192=2^18: safe
    const unsigned int* p = partials + (size_t)b * BLOCKS_PER_SAMPLE * NBINS;
#pragma unroll 8
    for (int j = 0; j < BLOCKS_PER_SAMPLE; ++j) {
        unsigned int v = p[(size_t)j * NBINS + tid];  // coalesced 1KB rows
        acc_s += v & SUM_MASK32;
        acc_c += v >> CNT_SHIFT32;
    }

    mean[tid] = ((float)acc_s * (1.0f / FIX_SCALE32)) / (float)acc_c;
    __syncthreads();

    float v = 0.0f;
    if (tid < NBINS - 1)
        v = fmaxf(mean[tid] - mean[tid + 1], 0.0f);

    for (int off = 32; off > 0; off >>= 1)
        v += __shfl_down(v, off, 64);
    if ((tid & 63) == 0) wsum[tid >> 6] = v;
    __syncthreads();
    if (tid == 0) {
        float loss_b = wsum[0] + wsum[1] + wsum[2] + wsum[3];
        atomicAdd(out, loss_b * (1.0f / (255.0f * (float)BATCH)));
    }
}

extern "C" void kernel_launch(void* const* d_in, const int* in_sizes, int n_in,
                              void* d_out, int out_size, void* d_ws, size_t ws_size,
                              hipStream_t stream)
{
    const float* img   = (const float*)d_in[0];
    const float* depth = (const float*)d_in[1];
    float* out = (float*)d_out;

    unsigned int* partials = (unsigned int*)d_ws;  // 1 MB, fully overwritten each call

    hist_kernel<<<NBLOCKS, 256, 0, stream>>>(img, depth, partials, out);
    reduce_kernel<<<BATCH, 256, 0, stream>>>(partials, out);
}

// Round 15
// 27.608 us; speedup vs baseline: 9.7566x; 1.0069x over previous
//
#include <hip/hip_runtime.h>

#define NBINS 256
#define BATCH 32
#define HW (512 * 512)
#define NSUB 4                 // per-wave sub-histograms (256 threads = 4 waves)
#define BLOCKS_PER_SAMPLE 32
#define NBLOCKS (BATCH * BLOCKS_PER_SAMPLE)  // 1024
#define NITER 8                // (HW/BLOCKS_PER_SAMPLE)/4/256

// Packed fixed-point u32 histogram cell (per block, 8192 px):
//   bits [0:17]  : sum of illum * 2^4   (block max 8192*16 = 2^17, illum<1)
//   bits [18:31] : count                (14 bits, max 16383 >= 8192 worst case)
#define CNT_SHIFT32 18
#define SUM_MASK32 ((1u << CNT_SHIFT32) - 1)
#define FIX_SCALE32 16.0f  // 2^4

__global__ __launch_bounds__(256) void hist_kernel(
    const float* __restrict__ img,        // [B,3,H,W]
    const float* __restrict__ depth,      // [B,1,H,W]
    unsigned int* __restrict__ partials,  // [NBLOCKS, NBINS] plain-stored
    float* __restrict__ out)              // zeroed here for reduce's atomics
{
    __shared__ unsigned int s_hist[NSUB][NBINS];  // 4 KB

    const int tid  = threadIdx.x;
    const int wave = tid >> 6;

    if (blockIdx.x == 0 && tid == 0) out[0] = 0.0f;

    for (int i = tid; i < NSUB * NBINS; i += 256)
        ((unsigned int*)s_hist)[i] = 0u;
    __syncthreads();

    const int b     = blockIdx.x / BLOCKS_PER_SAMPLE;
    const int chunk = blockIdx.x % BLOCKS_PER_SAMPLE;
    const int pixPerBlock = HW / BLOCKS_PER_SAMPLE;  // 8192
    const int base = chunk * pixPerBlock;

    const float4* Rp = (const float4*)(img + (size_t)b * 3 * HW + 0 * HW + base);
    const float4* Gp = (const float4*)(img + (size_t)b * 3 * HW + 1 * HW + base);
    const float4* Bp = (const float4*)(img + (size_t)b * 3 * HW + 2 * HW + base);
    const float4* Dp = (const float4*)(depth + (size_t)b * HW + base);

    // software-pipelined pixel loop (HBM-bound; kept from R14)
    float4 r  = Rp[tid];
    float4 g  = Gp[tid];
    float4 bl = Bp[tid];
    float4 d  = Dp[tid];

#pragma unroll
    for (int it = 0; it < NITER; ++it) {
        float4 rn, gn, bln, dn;
        if (it < NITER - 1) {
            const int j = tid + (it + 1) * 256;
            rn  = Rp[j];
            gn  = Gp[j];
            bln = Bp[j];
            dn  = Dp[j];
        }

        float il0 = 0.2f * r.x + 0.7f * g.x + 0.1f * bl.x;
        float il1 = 0.2f * r.y + 0.7f * g.y + 0.1f * bl.y;
        float il2 = 0.2f * r.z + 0.7f * g.z + 0.1f * bl.z;
        float il3 = 0.2f * r.w + 0.7f * g.w + 0.1f * bl.w;

        int k0 = (int)(d.x * 255.0f + 0.5f);
        int k1 = (int)(d.y * 255.0f + 0.5f);
        int k2 = (int)(d.z * 255.0f + 0.5f);
        int k3 = (int)(d.w * 255.0f + 0.5f);
        k0 = min(max(k0, 0), NBINS - 1);
        k1 = min(max(k1, 0), NBINS - 1);
        k2 = min(max(k2, 0), NBINS - 1);
        k3 = min(max(k3, 0), NBINS - 1);

        unsigned int v0 = (1u << CNT_SHIFT32) | (unsigned int)(il0 * FIX_SCALE32 + 0.5f);
        unsigned int v1 = (1u << CNT_SHIFT32) | (unsigned int)(il1 * FIX_SCALE32 + 0.5f);
        unsigned int v2 = (1u << CNT_SHIFT32) | (unsigned int)(il2 * FIX_SCALE32 + 0.5f);
        unsigned int v3 = (1u << CNT_SHIFT32) | (unsigned int)(il3 * FIX_SCALE32 + 0.5f);

        atomicAdd(&s_hist[wave][k0], v0);
        atomicAdd(&s_hist[wave][k1], v1);
        atomicAdd(&s_hist[wave][k2], v2);
        atomicAdd(&s_hist[wave][k3], v3);

        r = rn; g = gn; bl = bln; d = dn;
    }
    __syncthreads();

    // fold sub-histograms; plain coalesced store
    for (int k = tid; k < NBINS; k += 256) {
        unsigned int v = s_hist[0][k] + s_hist[1][k] + s_hist[2][k] + s_hist[3][k];
        partials[(size_t)blockIdx.x * NBINS + k] = v;
    }
}

// one block per sample, 1024 threads: 4 row-groups of 8 rows summed in
// parallel, fold in LDS, means, relu-diff, atomicAdd pre-scaled loss
__global__ __launch_bounds__(1024) void reduce_kernel(
    const unsigned int* __restrict__ partials,  // [NBLOCKS, NBINS]
    float* __restrict__ out)
{
    __shared__ unsigned int s_s[4][NBINS];  // 4 KB
    __shared__ unsigned int s_c[4][NBINS];  // 4 KB
    __shared__ float mean[NBINS];
    __shared__ float wsum[16];

    const int b   = blockIdx.x;
    const int tid = threadIdx.x;
    const int j   = tid >> 8;    // row group 0..3
    const int k   = tid & 255;   // bin

    const unsigned int* p = partials + (size_t)b * BLOCKS_PER_SAMPLE * NBINS;
    unsigned int as = 0u, ac = 0u;
#pragma unroll
    for (int r = j; r < BLOCKS_PER_SAMPLE; r += 4) {  // 8 coalesced rows/thread
        unsigned int v = p[(size_t)r * NBINS + k];
        as += v & SUM_MASK32;
        ac += v >> CNT_SHIFT32;
    }
    s_s[j][k] = as;
    s_c[j][k] = ac;
    __syncthreads();

    if (tid < NBINS) {
        unsigned int ts = s_s[0][k] + s_s[1][k] + s_s[2][k] + s_s[3][k];
        unsigned int tc = s_c[0][k] + s_c[1][k] + s_c[2][k] + s_c[3][k];
        mean[k] = ((float)ts * (1.0f / FIX_SCALE32)) / (float)tc;
    }
    __syncthreads();

    float v = 0.0f;
    if (tid < NBINS - 1)
        v = fmaxf(mean[tid] - mean[tid + 1], 0.0f);

    for (int off = 32; off > 0; off >>= 1)
        v += __shfl_down(v, off, 64);
    if ((tid & 63) == 0) wsum[tid >> 6] = v;
    __syncthreads();
    if (tid == 0) {
        float loss_b = 0.0f;
#pragma unroll
        for (int w = 0; w < 16; ++w) loss_b += wsum[w];
        atomicAdd(out, loss_b * (1.0f / (255.0f * (float)BATCH)));
    }
}

extern "C" void kernel_launch(void* const* d_in, const int* in_sizes, int n_in,
                              void* d_out, int out_size, void* d_ws, size_t ws_size,
                              hipStream_t stream)
{
    const float* img   = (const float*)d_in[0];
    const float* depth = (const float*)d_in[1];
    float* out = (float*)d_out;

    unsigned int* partials = (unsigned int*)d_ws;  // 1 MB, fully overwritten each call

    hist_kernel<<<NBLOCKS, 256, 0, stream>>>(img, depth, partials, out);
    reduce_kernel<<<BATCH, 1024, 0, stream>>>(partials, out);
}